// Round 15
// baseline (107.832 us; speedup 1.0000x reference)
//
#include <hip/hip_runtime.h>
#include <stdint.h>

#define BATCH 16
#define SEQ   4096
#define DIM   256
#define HW    64
#define NSTEP 10
#define DT    0.3f

typedef __attribute__((ext_vector_type(8))) short short8;   // 8 bf16 in 4 VGPRs
typedef __attribute__((ext_vector_type(4))) float f32x4;
typedef __attribute__((ext_vector_type(2))) float f32x2;

// ---------------------------------------------------------------------------
// Packed-f32 VOP3P helpers (throughput-neutral vs scalar per R8; kept for
// density). One SGPR source max per instruction.
// ---------------------------------------------------------------------------
__device__ __forceinline__ f32x2 pk_add(f32x2 a, f32x2 b) {
  f32x2 d; asm("v_pk_add_f32 %0, %1, %2" : "=v"(d) : "v"(a), "v"(b)); return d;
}
__device__ __forceinline__ f32x2 pk_mul(f32x2 a, f32x2 b) {
  f32x2 d; asm("v_pk_mul_f32 %0, %1, %2" : "=v"(d) : "v"(a), "v"(b)); return d;
}
// d = a*b + ks (addend in SGPR pair)
__device__ __forceinline__ f32x2 pk_fma_addk(f32x2 a, f32x2 b, f32x2 ks) {
  f32x2 d; asm("v_pk_fma_f32 %0, %1, %2, %3" : "=v"(d) : "v"(a), "v"(b), "s"(ks)); return d;
}
// d = a*ks + c (multiplier in SGPR pair)
__device__ __forceinline__ f32x2 pk_fma_s1(f32x2 a, f32x2 ks, f32x2 c) {
  f32x2 d; asm("v_pk_fma_f32 %0, %1, %2, %3" : "=v"(d) : "v"(a), "s"(ks), "v"(c)); return d;
}

// DPP lane shifts. With 16 lanes across, DPP 16-lane row boundaries coincide
// with plane edges: bound_ctrl zeroes the halo at lx==0 / lx==15 FOR FREE.
__device__ __forceinline__ float dpp_from_left(float x) {   // lane i <- lane i-1
  return __int_as_float(__builtin_amdgcn_update_dpp(
      0, __float_as_int(x), 0x111 /*row_shr:1*/, 0xF, 0xF, true));
}
__device__ __forceinline__ float dpp_from_right(float x) {  // lane i <- lane i+1
  return __int_as_float(__builtin_amdgcn_update_dpp(
      0, __float_as_int(x), 0x101 /*row_shl:1*/, 0xF, 0xF, true));
}

// round-to-nearest-even fp32 -> bf16 (bits in high 16)
__device__ __forceinline__ float bfhi(float a) {
  uint32_t u = __float_as_uint(a);
  u += 0x7FFFu + ((u >> 16) & 1u);
  return __uint_as_float(u & 0xFFFF0000u);
}
__device__ __forceinline__ uint32_t pack2(float a, float b) {
  uint32_t ua = __float_as_uint(a), ub = __float_as_uint(b);
  ua += 0x7FFFu + ((ua >> 16) & 1u);
  ub += 0x7FFFu + ((ub >> 16) & 1u);
  return (ua >> 16) | (ub & 0xFFFF0000u);
}

// ---------------------------------------------------------------------------
// GEMM: proj[(b*DIM+e)*SEQ + s] = sum_d x[b,s,d]*W[e,d] + bias[e]
// bf16x3 emulated-fp32 MFMA (unchanged; proven R3..R14).
// ---------------------------------------------------------------------------
__global__ __launch_bounds__(256) void gemm_proj_mfma(
    const float* __restrict__ x, const float* __restrict__ W,
    const float* __restrict__ bias, float* __restrict__ proj) {
  const int eTile = blockIdx.x * 128;
  const int sTile = blockIdx.y * 128;
  const int b     = blockIdx.z;
  const int t     = threadIdx.x;
  const int lane  = t & 63;
  const int wid   = t >> 6;
  const int wr    = wid >> 1;
  const int wc    = wid & 1;

  __shared__ char lds[4 * 128 * 80];
  char* Whs = lds;
  char* Wls = lds + 10240;
  char* Xhs = lds + 20480;
  char* Xls = lds + 30720;

  const float* xb = x + (size_t)b * SEQ * DIM;

  f32x4 acc[4][4] = {};
  float4 regW[4], regX[4];

#define ISSUE_LOADS(KT)                                                        \
  {                                                                            \
    _Pragma("unroll")                                                          \
    for (int r = 0; r < 4; r++) {                                              \
      int ci = t + 256 * r;                                                    \
      int row = ci >> 3, q = ci & 7;                                           \
      regW[r] = *(const float4*)(W  + (size_t)(eTile + row) * DIM + (KT) + q * 4); \
      regX[r] = *(const float4*)(xb + (size_t)(sTile + row) * DIM + (KT) + q * 4); \
    }                                                                          \
  }

  ISSUE_LOADS(0);

  for (int kt = 0; kt < DIM; kt += 32) {
    __syncthreads();
#pragma unroll
    for (int r = 0; r < 4; r++) {
      int ci = t + 256 * r;
      int row = ci >> 3, q = ci & 7;
      float4 v = regW[r];
      uint2 hi, lo;
      hi.x = pack2(v.x, v.y); hi.y = pack2(v.z, v.w);
      lo.x = pack2(v.x - bfhi(v.x), v.y - bfhi(v.y));
      lo.y = pack2(v.z - bfhi(v.z), v.w - bfhi(v.w));
      *(uint2*)(Whs + row * 80 + q * 8) = hi;
      *(uint2*)(Wls + row * 80 + q * 8) = lo;
      v = regX[r];
      hi.x = pack2(v.x, v.y); hi.y = pack2(v.z, v.w);
      lo.x = pack2(v.x - bfhi(v.x), v.y - bfhi(v.y));
      lo.y = pack2(v.z - bfhi(v.z), v.w - bfhi(v.w));
      *(uint2*)(Xhs + row * 80 + q * 8) = hi;
      *(uint2*)(Xls + row * 80 + q * 8) = lo;
    }
    __syncthreads();

    if (kt + 32 < DIM) ISSUE_LOADS(kt + 32);

    const int c16 = (lane >> 4) * 16;
    const int rlo = lane & 15;
    short8 bh[4], bl[4];
#pragma unroll
    for (int j = 0; j < 4; j++) {
      int rowX = wc * 64 + j * 16 + rlo;
      bh[j] = *(const short8*)(Xhs + rowX * 80 + c16);
      bl[j] = *(const short8*)(Xls + rowX * 80 + c16);
    }
#pragma unroll
    for (int i = 0; i < 4; i++) {
      int rowW = wr * 64 + i * 16 + rlo;
      short8 ah = *(const short8*)(Whs + rowW * 80 + c16);
      short8 al = *(const short8*)(Wls + rowW * 80 + c16);
#pragma unroll
      for (int j = 0; j < 4; j++) {
        acc[i][j] = __builtin_amdgcn_mfma_f32_16x16x32_bf16(ah, bh[j], acc[i][j], 0, 0, 0);
        acc[i][j] = __builtin_amdgcn_mfma_f32_16x16x32_bf16(ah, bl[j], acc[i][j], 0, 0, 0);
        acc[i][j] = __builtin_amdgcn_mfma_f32_16x16x32_bf16(al, bh[j], acc[i][j], 0, 0, 0);
      }
    }
  }
#undef ISSUE_LOADS

#pragma unroll
  for (int i = 0; i < 4; i++) {
    int e0 = eTile + wr * 64 + i * 16 + (lane >> 4) * 4;
#pragma unroll
    for (int reg = 0; reg < 4; reg++) {
      int e = e0 + reg;
      float bb = bias[e];
      float* orow = proj + ((size_t)(b * DIM + e)) * SEQ + sTile + wc * 64;
#pragma unroll
      for (int j = 0; j < 4; j++)
        orow[j * 16 + (lane & 15)] = acc[i][j][reg] + bb;
    }
  }
}

// ---------------------------------------------------------------------------
// Evolve: ONE wave per plane (no barriers, no LDS, no partner exchange).
// Lane = 16 rows x 4 cols; u[16][2] f32x2 = 64 VGPR state.
// R14 lesson: __launch_bounds__(256,4) made the allocator TARGET 8 waves/EU
// (64-VGPR cap) and spill 16 MB/dispatch. amdgpu_waves_per_eu(4,4) pins
// min=max=4 -> 128-VGPR budget, kernel needs ~98 -> no scratch.
// Row-compute identical to R13/R14 (DPP side halos with free edge zeroing,
// Pade[5/4]+Ac-fold tanh, shared rcp per 4 cells). 4096 waves = 4/SIMD.
// ---------------------------------------------------------------------------
__attribute__((amdgpu_waves_per_eu(4, 4)))
__global__ __launch_bounds__(256) void evolve_kernel(
    const float* __restrict__ proj, const float* __restrict__ dcoef,
    float* __restrict__ out) {
  const int tid   = threadIdx.x;
  const int wid   = tid >> 6;
  const int lane  = tid & 63;
  const int plane = blockIdx.x * 4 + wid;  // = b*DIM + e
  const int lx = lane & 15;                // col block (4 cols)
  const int ly = lane >> 4;                // row block (16 rows)

  const float D   = dcoef[0];
  const float DDf = DT * D;
  const float Acf = 1.f - DT - 4.f * DDf;
  const float DDu = __uint_as_float(__builtin_amdgcn_readfirstlane(__float_as_uint(DDf)));
  const float Acu = __uint_as_float(__builtin_amdgcn_readfirstlane(__float_as_uint(Acf)));
  // Pade[5/4] fold: P(y) = (DT + 6*Ac)*y + 15*(DT + Ac);  Dn(y) = 6y + 15
  const float PAf = DT + 6.f * Acu;
  const float P0f = 15.f * (DT + Acu);
  const float P0u = __uint_as_float(__builtin_amdgcn_readfirstlane(__float_as_uint(P0f)));
  const f32x2 kDD  = {DDu, DDu};           // SGPR pair
  const f32x2 kP0  = {P0u, P0u};           // SGPR pair
  const f32x2 k15  = {15.f, 15.f};         // SGPR pair
  const f32x2 kPAv = {PAf, PAf};           // VGPR pair (multiplier slot)
  const f32x2 k6v  = {6.f, 6.f};           // VGPR pair

  const float* p = proj + (size_t)plane * (HW * HW)
                 + (size_t)(ly * 16) * HW + lx * 4;

  // u[r][q]: r = 0..15 rows, q = 0..1 col-pairs (4 cols/lane)
  f32x2 u[16][2];
#pragma unroll
  for (int r = 0; r < 16; r++) {
    float4 v = *(const float4*)(p + r * HW);
    u[r][0] = f32x2{v.x, v.y};
    u[r][1] = f32x2{v.z, v.w};
  }

  // 4 cells (2 pairs), shared reciprocal: z = sv*P(y)/Dn(y) + DD*s4
  auto pair2 = [&](f32x2 svA, f32x2 svB, f32x2 s4A, f32x2 s4B,
                   f32x2& zA, f32x2& zB) {
    f32x2 yA = pk_mul(svA, svA), yB = pk_mul(svB, svB);
    f32x2 tA = pk_fma_addk(yA, kPAv, kP0);
    f32x2 tB = pk_fma_addk(yB, kPAv, kP0);
    f32x2 nA = pk_mul(svA, tA);
    f32x2 nB = pk_mul(svB, tB);
    f32x2 dA = pk_fma_addk(yA, k6v, k15);
    f32x2 dB = pk_fma_addk(yB, k6v, k15);
    float pA = dA.x * dA.y, qB = dB.x * dB.y;
    float rr = __builtin_amdgcn_rcpf(pA * qB);
    float qr = qB * rr, pr = pA * rr;      // 1/pA, 1/qB
    f32x2 iA; iA.x = dA.y * qr; iA.y = dA.x * qr;
    f32x2 iB; iB.x = dB.y * pr; iB.y = dB.x * pr;
    zA = pk_fma_s1(s4A, kDD, pk_mul(nA, iA));
    zB = pk_fma_s1(s4B, kDD, pk_mul(nB, iB));
  };

#pragma unroll 1
  for (int step = 0; step < NSTEP; step++) {
    // halo prefetch (all OLD; shfl unconditional, then select — R4 lesson).
    // top halo (row above lane's row0) = lane-16's row15; ly==0 -> plane edge 0
    float ax0 = __shfl(u[15][0].x, (lane - 16) & 63);
    float ay0 = __shfl(u[15][0].y, (lane - 16) & 63);
    float ax1 = __shfl(u[15][1].x, (lane - 16) & 63);
    float ay1 = __shfl(u[15][1].y, (lane - 16) & 63);
    f32x2 th0, th1;
    th0.x = (ly == 0) ? 0.f : ax0;
    th0.y = (ly == 0) ? 0.f : ay0;
    th1.x = (ly == 0) ? 0.f : ax1;
    th1.y = (ly == 0) ? 0.f : ay1;
    // bottom halo (row below lane's row15) = lane+16's row0; ly==3 -> 0
    float bx0 = __shfl(u[0][0].x, (lane + 16) & 63);
    float by0 = __shfl(u[0][0].y, (lane + 16) & 63);
    float bx1 = __shfl(u[0][1].x, (lane + 16) & 63);
    float by1 = __shfl(u[0][1].y, (lane + 16) & 63);
    f32x2 bh0, bh1;
    bh0.x = (ly == 3) ? 0.f : bx0;
    bh0.y = (ly == 3) ? 0.f : by0;
    bh1.x = (ly == 3) ? 0.f : bx1;
    bh1.y = (ly == 3) ? 0.f : by1;

    // rows 0..15 in order, in place, rolling prev; side halos JIT via DPP
    f32x2 prev0 = th0, prev1 = th1;
#pragma unroll
    for (int r = 0; r < 16; r++) {
      f32x2 sv0 = u[r][0], sv1 = u[r][1];
      float lfv = dpp_from_left(sv1.y);    // zero at lx==0 by bound_ctrl
      float rtv = dpp_from_right(sv0.x);   // zero at lx==15
      f32x2 dn0 = (r < 15) ? u[r + 1][0] : bh0;
      f32x2 dn1 = (r < 15) ? u[r + 1][1] : bh1;
      f32x2 hs0, hs1;
      hs0.x = lfv + sv0.y;   hs0.y = sv0.x + sv1.x;
      hs1.x = sv0.y + sv1.y; hs1.y = sv1.x + rtv;
      f32x2 s40 = pk_add(pk_add(prev0, dn0), hs0);
      f32x2 s41 = pk_add(pk_add(prev1, dn1), hs1);
      pair2(sv0, sv1, s40, s41, u[r][0], u[r][1]);
      prev0 = sv0; prev1 = sv1;
    }
  }

  // spatial mean: pure wave reduce (no LDS)
  float s = 0.f;
#pragma unroll
  for (int r = 0; r < 16; r++)
#pragma unroll
    for (int q = 0; q < 2; q++) s += u[r][q].x + u[r][q].y;
#pragma unroll
  for (int off = 32; off > 0; off >>= 1) s += __shfl_xor(s, off);
  if (lane == 0) out[plane] = s * (1.f / (HW * HW));
}

// ---------------------------------------------------------------------------
extern "C" void kernel_launch(void* const* d_in, const int* in_sizes, int n_in,
                              void* d_out, int out_size, void* d_ws, size_t ws_size,
                              hipStream_t stream) {
  const float* x    = (const float*)d_in[0];
  const float* W    = (const float*)d_in[1];
  const float* bias = (const float*)d_in[2];
  const float* dc   = (const float*)d_in[3];
  float* out  = (float*)d_out;
  float* proj = (float*)d_ws;   // BATCH*DIM*SEQ*4 = 64 MB

  dim3 g1(DIM / 128, SEQ / 128, BATCH);
  gemm_proj_mfma<<<g1, 256, 0, stream>>>(x, W, bias, proj);

  evolve_kernel<<<(BATCH * DIM) / 4, 256, 0, stream>>>(proj, dc, out);
}

// Round 16
// 104.587 us; speedup vs baseline: 1.0310x; 1.0310x over previous
//
#include <hip/hip_runtime.h>
#include <stdint.h>

#define BATCH 16
#define SEQ   4096
#define DIM   256
#define HW    64
#define NSTEP 10
#define DT    0.3f

typedef __attribute__((ext_vector_type(8))) short short8;   // 8 bf16 in 4 VGPRs
typedef __attribute__((ext_vector_type(4))) float f32x4;
typedef __attribute__((ext_vector_type(2))) float f32x2;

// ---------------------------------------------------------------------------
// Packed-f32 VOP3P helpers (throughput-neutral vs scalar per R8; halve the
// instruction count). One SGPR source max per instruction.
// ---------------------------------------------------------------------------
__device__ __forceinline__ f32x2 pk_add(f32x2 a, f32x2 b) {
  f32x2 d; asm("v_pk_add_f32 %0, %1, %2" : "=v"(d) : "v"(a), "v"(b)); return d;
}
__device__ __forceinline__ f32x2 pk_mul(f32x2 a, f32x2 b) {
  f32x2 d; asm("v_pk_mul_f32 %0, %1, %2" : "=v"(d) : "v"(a), "v"(b)); return d;
}
// d = a*b + ks (addend in SGPR pair)
__device__ __forceinline__ f32x2 pk_fma_addk(f32x2 a, f32x2 b, f32x2 ks) {
  f32x2 d; asm("v_pk_fma_f32 %0, %1, %2, %3" : "=v"(d) : "v"(a), "v"(b), "s"(ks)); return d;
}
// d = a*ks + c (multiplier in SGPR pair)
__device__ __forceinline__ f32x2 pk_fma_s1(f32x2 a, f32x2 ks, f32x2 c) {
  f32x2 d; asm("v_pk_fma_f32 %0, %1, %2, %3" : "=v"(d) : "v"(a), "s"(ks), "v"(c)); return d;
}

// DPP lane shifts. With 16 lanes across, DPP 16-lane row boundaries coincide
// with plane edges: bound_ctrl zeroes the halo at lx==0 / lx==15 FOR FREE.
__device__ __forceinline__ float dpp_from_left(float x) {   // lane i <- lane i-1
  return __int_as_float(__builtin_amdgcn_update_dpp(
      0, __float_as_int(x), 0x111 /*row_shr:1*/, 0xF, 0xF, true));
}
__device__ __forceinline__ float dpp_from_right(float x) {  // lane i <- lane i+1
  return __int_as_float(__builtin_amdgcn_update_dpp(
      0, __float_as_int(x), 0x101 /*row_shl:1*/, 0xF, 0xF, true));
}

// round-to-nearest-even fp32 -> bf16 (bits in high 16)
__device__ __forceinline__ float bfhi(float a) {
  uint32_t u = __float_as_uint(a);
  u += 0x7FFFu + ((u >> 16) & 1u);
  return __uint_as_float(u & 0xFFFF0000u);
}
__device__ __forceinline__ uint32_t pack2(float a, float b) {
  uint32_t ua = __float_as_uint(a), ub = __float_as_uint(b);
  ua += 0x7FFFu + ((ua >> 16) & 1u);
  ub += 0x7FFFu + ((ub >> 16) & 1u);
  return (ua >> 16) | (ub & 0xFFFF0000u);
}

// ---------------------------------------------------------------------------
// GEMM: proj[(b*DIM+e)*SEQ + s] = sum_d x[b,s,d]*W[e,d] + bias[e]
// bf16x3 emulated-fp32 MFMA (unchanged; proven R3..R15; ~24-28 us, near
// its HBM/L2 floor of ~20 us).
// ---------------------------------------------------------------------------
__global__ __launch_bounds__(256) void gemm_proj_mfma(
    const float* __restrict__ x, const float* __restrict__ W,
    const float* __restrict__ bias, float* __restrict__ proj) {
  const int eTile = blockIdx.x * 128;
  const int sTile = blockIdx.y * 128;
  const int b     = blockIdx.z;
  const int t     = threadIdx.x;
  const int lane  = t & 63;
  const int wid   = t >> 6;
  const int wr    = wid >> 1;
  const int wc    = wid & 1;

  __shared__ char lds[4 * 128 * 80];
  char* Whs = lds;
  char* Wls = lds + 10240;
  char* Xhs = lds + 20480;
  char* Xls = lds + 30720;

  const float* xb = x + (size_t)b * SEQ * DIM;

  f32x4 acc[4][4] = {};
  float4 regW[4], regX[4];

#define ISSUE_LOADS(KT)                                                        \
  {                                                                            \
    _Pragma("unroll")                                                          \
    for (int r = 0; r < 4; r++) {                                              \
      int ci = t + 256 * r;                                                    \
      int row = ci >> 3, q = ci & 7;                                           \
      regW[r] = *(const float4*)(W  + (size_t)(eTile + row) * DIM + (KT) + q * 4); \
      regX[r] = *(const float4*)(xb + (size_t)(sTile + row) * DIM + (KT) + q * 4); \
    }                                                                          \
  }

  ISSUE_LOADS(0);

  for (int kt = 0; kt < DIM; kt += 32) {
    __syncthreads();
#pragma unroll
    for (int r = 0; r < 4; r++) {
      int ci = t + 256 * r;
      int row = ci >> 3, q = ci & 7;
      float4 v = regW[r];
      uint2 hi, lo;
      hi.x = pack2(v.x, v.y); hi.y = pack2(v.z, v.w);
      lo.x = pack2(v.x - bfhi(v.x), v.y - bfhi(v.y));
      lo.y = pack2(v.z - bfhi(v.z), v.w - bfhi(v.w));
      *(uint2*)(Whs + row * 80 + q * 8) = hi;
      *(uint2*)(Wls + row * 80 + q * 8) = lo;
      v = regX[r];
      hi.x = pack2(v.x, v.y); hi.y = pack2(v.z, v.w);
      lo.x = pack2(v.x - bfhi(v.x), v.y - bfhi(v.y));
      lo.y = pack2(v.z - bfhi(v.z), v.w - bfhi(v.w));
      *(uint2*)(Xhs + row * 80 + q * 8) = hi;
      *(uint2*)(Xls + row * 80 + q * 8) = lo;
    }
    __syncthreads();

    if (kt + 32 < DIM) ISSUE_LOADS(kt + 32);

    const int c16 = (lane >> 4) * 16;
    const int rlo = lane & 15;
    short8 bh[4], bl[4];
#pragma unroll
    for (int j = 0; j < 4; j++) {
      int rowX = wc * 64 + j * 16 + rlo;
      bh[j] = *(const short8*)(Xhs + rowX * 80 + c16);
      bl[j] = *(const short8*)(Xls + rowX * 80 + c16);
    }
#pragma unroll
    for (int i = 0; i < 4; i++) {
      int rowW = wr * 64 + i * 16 + rlo;
      short8 ah = *(const short8*)(Whs + rowW * 80 + c16);
      short8 al = *(const short8*)(Wls + rowW * 80 + c16);
#pragma unroll
      for (int j = 0; j < 4; j++) {
        acc[i][j] = __builtin_amdgcn_mfma_f32_16x16x32_bf16(ah, bh[j], acc[i][j], 0, 0, 0);
        acc[i][j] = __builtin_amdgcn_mfma_f32_16x16x32_bf16(ah, bl[j], acc[i][j], 0, 0, 0);
        acc[i][j] = __builtin_amdgcn_mfma_f32_16x16x32_bf16(al, bh[j], acc[i][j], 0, 0, 0);
      }
    }
  }
#undef ISSUE_LOADS

#pragma unroll
  for (int i = 0; i < 4; i++) {
    int e0 = eTile + wr * 64 + i * 16 + (lane >> 4) * 4;
#pragma unroll
    for (int reg = 0; reg < 4; reg++) {
      int e = e0 + reg;
      float bb = bias[e];
      float* orow = proj + ((size_t)(b * DIM + e)) * SEQ + sTile + wc * 64;
#pragma unroll
      for (int j = 0; j < 4; j++)
        orow[j * 16 + (lane & 15)] = acc[i][j][reg] + bb;
    }
  }
}

// ---------------------------------------------------------------------------
// Evolve: block = 256 thr = 4 waves = 1 plane; wave w owns rows [16w,16w+16).
// R14/R15 lesson: the allocator insists on the 8-waves/EU 64-VGPR target and
// spills anything bigger — so make the kernel FIT 64: lane = 4 rows x 4 cols,
// u[4][2] = 8 VGPR state, ~45 total. 16 waves/SIMD of work, 8 resident ->
// 2x R13's latency hiding, zero spill risk. Boundary rows via tiny
// double-buffered LDS table (4 KB), one barrier/step, end-of-step publish.
// Row compute identical to R13/R14 (DPP side halos with free edge zeroing,
// Pade[5/4]+Ac-fold tanh, shared rcp per 4 cells). All cross-lane ops on OLD
// values, unconditional-then-select (R4 lesson).
// ---------------------------------------------------------------------------
__global__ __launch_bounds__(256) void evolve_kernel(
    const float* __restrict__ proj, const float* __restrict__ dcoef,
    float* __restrict__ out) {
  const int tid   = threadIdx.x;
  const int w     = tid >> 6;              // wave 0..3: rows [16w, 16w+16)
  const int lane  = tid & 63;
  const int plane = blockIdx.x;            // = b*DIM + e
  const int lx = lane & 15;                // col block (4 cols)
  const int ly = lane >> 4;                // row block (4 rows)

  __shared__ float bnd[2][4][2][64];       // [buf][wave][side: 0=row0,1=row15][col]
  __shared__ float psum[4];

  const float D   = dcoef[0];
  const float DDf = DT * D;
  const float Acf = 1.f - DT - 4.f * DDf;
  const float DDu = __uint_as_float(__builtin_amdgcn_readfirstlane(__float_as_uint(DDf)));
  const float Acu = __uint_as_float(__builtin_amdgcn_readfirstlane(__float_as_uint(Acf)));
  // Pade[5/4] fold: P(y) = (DT + 6*Ac)*y + 15*(DT + Ac);  Dn(y) = 6y + 15
  const float PAf = DT + 6.f * Acu;
  const float P0f = 15.f * (DT + Acu);
  const float P0u = __uint_as_float(__builtin_amdgcn_readfirstlane(__float_as_uint(P0f)));
  const f32x2 kDD  = {DDu, DDu};           // SGPR pair
  const f32x2 kP0  = {P0u, P0u};           // SGPR pair
  const f32x2 k15  = {15.f, 15.f};         // SGPR pair
  const f32x2 kPAv = {PAf, PAf};           // VGPR pair (multiplier slot)
  const f32x2 k6v  = {6.f, 6.f};           // VGPR pair

  const float* p = proj + (size_t)plane * (HW * HW)
                 + (size_t)(w * 16 + ly * 4) * HW + lx * 4;

  // u[r][q]: r = 0..3 rows, q = 0..1 col-pairs (4 cols/lane)
  f32x2 u[4][2];
#pragma unroll
  for (int r = 0; r < 4; r++) {
    float4 v = *(const float4*)(p + r * HW);
    u[r][0] = f32x2{v.x, v.y};
    u[r][1] = f32x2{v.z, v.w};
  }

  // 4 cells (2 pairs), shared reciprocal: z = sv*P(y)/Dn(y) + DD*s4
  auto pair2 = [&](f32x2 svA, f32x2 svB, f32x2 s4A, f32x2 s4B,
                   f32x2& zA, f32x2& zB) {
    f32x2 yA = pk_mul(svA, svA), yB = pk_mul(svB, svB);
    f32x2 tA = pk_fma_addk(yA, kPAv, kP0);
    f32x2 tB = pk_fma_addk(yB, kPAv, kP0);
    f32x2 nA = pk_mul(svA, tA);
    f32x2 nB = pk_mul(svB, tB);
    f32x2 dA = pk_fma_addk(yA, k6v, k15);
    f32x2 dB = pk_fma_addk(yB, k6v, k15);
    float pA = dA.x * dA.y, qB = dB.x * dB.y;
    float rr = __builtin_amdgcn_rcpf(pA * qB);
    float qr = qB * rr, pr = pA * rr;      // 1/pA, 1/qB
    f32x2 iA; iA.x = dA.y * qr; iA.y = dA.x * qr;
    f32x2 iB; iB.x = dB.y * pr; iB.y = dB.x * pr;
    zA = pk_fma_s1(s4A, kDD, pk_mul(nA, iA));
    zB = pk_fma_s1(s4B, kDD, pk_mul(nB, iB));
  };

  // prologue: publish OLD boundary rows into buf 0
  if (ly == 0) {
    float4 pub; pub.x = u[0][0].x; pub.y = u[0][0].y;
    pub.z = u[0][1].x; pub.w = u[0][1].y;
    *(float4*)&bnd[0][w][0][lx * 4] = pub;       // wave's row0 (global 16w)
  }
  if (ly == 3) {
    float4 pub; pub.x = u[3][0].x; pub.y = u[3][0].y;
    pub.z = u[3][1].x; pub.w = u[3][1].y;
    *(float4*)&bnd[0][w][1][lx * 4] = pub;       // wave's row15 (global 16w+15)
  }
  __syncthreads();

  const int wup = (w > 0) ? w - 1 : 0;     // wave-uniform clamped indices
  const int wdn = (w < 3) ? w + 1 : 3;

#pragma unroll 1
  for (int step = 0; step < NSTEP; step++) {
    const int rb = step & 1, wb = rb ^ 1;
    // neighbor-wave boundary rows (previous-step values; unconditional reads)
    float4 nbt = *(const float4*)&bnd[rb][wup][1][lx * 4];  // row above (w-1's row15)
    float4 nbb = *(const float4*)&bnd[rb][wdn][0][lx * 4];  // row below (w+1's row0)

    // intra-wave top/bottom halos (OLD; shfl unconditional, then select)
    float ax0 = __shfl(u[3][0].x, (lane - 16) & 63);
    float ay0 = __shfl(u[3][0].y, (lane - 16) & 63);
    float ax1 = __shfl(u[3][1].x, (lane - 16) & 63);
    float ay1 = __shfl(u[3][1].y, (lane - 16) & 63);
    f32x2 th0, th1;
    th0.x = (ly == 0) ? ((w > 0) ? nbt.x : 0.f) : ax0;
    th0.y = (ly == 0) ? ((w > 0) ? nbt.y : 0.f) : ay0;
    th1.x = (ly == 0) ? ((w > 0) ? nbt.z : 0.f) : ax1;
    th1.y = (ly == 0) ? ((w > 0) ? nbt.w : 0.f) : ay1;
    float bx0 = __shfl(u[0][0].x, (lane + 16) & 63);
    float by0 = __shfl(u[0][0].y, (lane + 16) & 63);
    float bx1 = __shfl(u[0][1].x, (lane + 16) & 63);
    float by1 = __shfl(u[0][1].y, (lane + 16) & 63);
    f32x2 bh0, bh1;
    bh0.x = (ly == 3) ? ((w < 3) ? nbb.x : 0.f) : bx0;
    bh0.y = (ly == 3) ? ((w < 3) ? nbb.y : 0.f) : by0;
    bh1.x = (ly == 3) ? ((w < 3) ? nbb.z : 0.f) : bx1;
    bh1.y = (ly == 3) ? ((w < 3) ? nbb.w : 0.f) : by1;

    // rows 0..3 in order, in place, rolling prev; side halos JIT via DPP
    f32x2 prev0 = th0, prev1 = th1;
#pragma unroll
    for (int r = 0; r < 4; r++) {
      f32x2 sv0 = u[r][0], sv1 = u[r][1];
      float lfv = dpp_from_left(sv1.y);    // zero at lx==0 by bound_ctrl
      float rtv = dpp_from_right(sv0.x);   // zero at lx==15
      f32x2 dn0 = (r < 3) ? u[r + 1][0] : bh0;
      f32x2 dn1 = (r < 3) ? u[r + 1][1] : bh1;
      f32x2 hs0, hs1;
      hs0.x = lfv + sv0.y;   hs0.y = sv0.x + sv1.x;
      hs1.x = sv0.y + sv1.y; hs1.y = sv1.x + rtv;
      f32x2 s40 = pk_add(pk_add(prev0, dn0), hs0);
      f32x2 s41 = pk_add(pk_add(prev1, dn1), hs1);
      pair2(sv0, sv1, s40, s41, u[r][0], u[r][1]);
      prev0 = sv0; prev1 = sv1;
    }

    // publish NEW boundary rows into the other buffer (next step's old)
    if (ly == 0) {
      float4 pub; pub.x = u[0][0].x; pub.y = u[0][0].y;
      pub.z = u[0][1].x; pub.w = u[0][1].y;
      *(float4*)&bnd[wb][w][0][lx * 4] = pub;
    }
    if (ly == 3) {
      float4 pub; pub.x = u[3][0].x; pub.y = u[3][0].y;
      pub.z = u[3][1].x; pub.w = u[3][1].y;
      *(float4*)&bnd[wb][w][1][lx * 4] = pub;
    }
    __syncthreads();   // one barrier per step
  }

  // spatial mean: wave-reduce 16 cells, combine 4 waves via LDS
  float s = 0.f;
#pragma unroll
  for (int r = 0; r < 4; r++)
#pragma unroll
    for (int q = 0; q < 2; q++) s += u[r][q].x + u[r][q].y;
#pragma unroll
  for (int off = 32; off > 0; off >>= 1) s += __shfl_xor(s, off);
  if (lane == 0) psum[w] = s;
  __syncthreads();
  if (w == 0 && lane == 0)
    out[plane] = (psum[0] + psum[1] + psum[2] + psum[3]) * (1.f / (HW * HW));
}

// ---------------------------------------------------------------------------
extern "C" void kernel_launch(void* const* d_in, const int* in_sizes, int n_in,
                              void* d_out, int out_size, void* d_ws, size_t ws_size,
                              hipStream_t stream) {
  const float* x    = (const float*)d_in[0];
  const float* W    = (const float*)d_in[1];
  const float* bias = (const float*)d_in[2];
  const float* dc   = (const float*)d_in[3];
  float* out  = (float*)d_out;
  float* proj = (float*)d_ws;   // BATCH*DIM*SEQ*4 = 64 MB

  dim3 g1(DIM / 128, SEQ / 128, BATCH);
  gemm_proj_mfma<<<g1, 256, 0, stream>>>(x, W, bias, proj);

  evolve_kernel<<<BATCH * DIM, 256, 0, stream>>>(proj, dc, out);
}

// Round 17
// 98.886 us; speedup vs baseline: 1.0905x; 1.0577x over previous
//
#include <hip/hip_runtime.h>
#include <stdint.h>

#define BATCH 16
#define SEQ   4096
#define DIM   256
#define HW    64
#define NSTEP 10
#define DT    0.3f

typedef __attribute__((ext_vector_type(8))) short short8;   // 8 bf16 in 4 VGPRs
typedef __attribute__((ext_vector_type(4))) float f32x4;
typedef __attribute__((ext_vector_type(2))) float f32x2;

// ---------------------------------------------------------------------------
// Packed-f32 VOP3P helpers (throughput-neutral vs scalar per R8).
// ---------------------------------------------------------------------------
__device__ __forceinline__ f32x2 pk_add(f32x2 a, f32x2 b) {
  f32x2 d; asm("v_pk_add_f32 %0, %1, %2" : "=v"(d) : "v"(a), "v"(b)); return d;
}
__device__ __forceinline__ f32x2 pk_mul(f32x2 a, f32x2 b) {
  f32x2 d; asm("v_pk_mul_f32 %0, %1, %2" : "=v"(d) : "v"(a), "v"(b)); return d;
}
__device__ __forceinline__ f32x2 pk_fma_addk(f32x2 a, f32x2 b, f32x2 ks) {
  f32x2 d; asm("v_pk_fma_f32 %0, %1, %2, %3" : "=v"(d) : "v"(a), "v"(b), "s"(ks)); return d;
}
__device__ __forceinline__ f32x2 pk_fma_s1(f32x2 a, f32x2 ks, f32x2 c) {
  f32x2 d; asm("v_pk_fma_f32 %0, %1, %2, %3" : "=v"(d) : "v"(a), "s"(ks), "v"(c)); return d;
}

// DPP lane shifts (16-lane rows align with plane edges; bound_ctrl zeroes).
__device__ __forceinline__ float dpp_from_left(float x) {
  return __int_as_float(__builtin_amdgcn_update_dpp(
      0, __float_as_int(x), 0x111, 0xF, 0xF, true));
}
__device__ __forceinline__ float dpp_from_right(float x) {
  return __int_as_float(__builtin_amdgcn_update_dpp(
      0, __float_as_int(x), 0x101, 0xF, 0xF, true));
}

// ---------------------------------------------------------------------------
// R17: fp32 -> (bf16-hi, bf16-lo) split via TRUNCATE + v_perm pair-pack.
// hi = bits & 0xFFFF0000 (1 AND); lo = x - hi (1 SUB, exact); pack the hi16
// halves of two regs with ONE v_perm_b32 (sel 0x07060302: dst.lo16 = src1.hi16,
// dst.hi16 = src0.hi16). 12 VALU/float4 vs 36 for round-and-pack (R3..R16).
// Accuracy: |lo| <= 2^-7|x| so dropped xl*wl ~ 2^-14 rel (~1e-4 abs/cell),
// independent per cell -> ~2e-6 after the 4096-cell spatial mean. Safe.
// ---------------------------------------------------------------------------
__device__ __forceinline__ void split_pack(float4 v, uint2& hi, uint2& lo) {
  uint32_t u0 = __float_as_uint(v.x), u1 = __float_as_uint(v.y);
  uint32_t u2 = __float_as_uint(v.z), u3 = __float_as_uint(v.w);
  float h0 = __uint_as_float(u0 & 0xFFFF0000u);
  float h1 = __uint_as_float(u1 & 0xFFFF0000u);
  float h2 = __uint_as_float(u2 & 0xFFFF0000u);
  float h3 = __uint_as_float(u3 & 0xFFFF0000u);
  hi.x = __builtin_amdgcn_perm(u1, u0, 0x07060302u);
  hi.y = __builtin_amdgcn_perm(u3, u2, 0x07060302u);
  lo.x = __builtin_amdgcn_perm(__float_as_uint(v.y - h1),
                               __float_as_uint(v.x - h0), 0x07060302u);
  lo.y = __builtin_amdgcn_perm(__float_as_uint(v.w - h3),
                               __float_as_uint(v.z - h2), 0x07060302u);
}

// ---------------------------------------------------------------------------
// GEMM: proj[(b*DIM+e)*SEQ + s] = sum_d x[b,s,d]*W[e,d] + bias[e]
// bf16x3 emulated-fp32 MFMA; staging conversion now 3x cheaper (split_pack).
// ---------------------------------------------------------------------------
__global__ __launch_bounds__(256) void gemm_proj_mfma(
    const float* __restrict__ x, const float* __restrict__ W,
    const float* __restrict__ bias, float* __restrict__ proj) {
  const int eTile = blockIdx.x * 128;
  const int sTile = blockIdx.y * 128;
  const int b     = blockIdx.z;
  const int t     = threadIdx.x;
  const int lane  = t & 63;
  const int wid   = t >> 6;
  const int wr    = wid >> 1;
  const int wc    = wid & 1;

  __shared__ char lds[4 * 128 * 80];
  char* Whs = lds;
  char* Wls = lds + 10240;
  char* Xhs = lds + 20480;
  char* Xls = lds + 30720;

  const float* xb = x + (size_t)b * SEQ * DIM;

  f32x4 acc[4][4] = {};
  float4 regW[4], regX[4];

#define ISSUE_LOADS(KT)                                                        \
  {                                                                            \
    _Pragma("unroll")                                                          \
    for (int r = 0; r < 4; r++) {                                              \
      int ci = t + 256 * r;                                                    \
      int row = ci >> 3, q = ci & 7;                                           \
      regW[r] = *(const float4*)(W  + (size_t)(eTile + row) * DIM + (KT) + q * 4); \
      regX[r] = *(const float4*)(xb + (size_t)(sTile + row) * DIM + (KT) + q * 4); \
    }                                                                          \
  }

  ISSUE_LOADS(0);

  for (int kt = 0; kt < DIM; kt += 32) {
    __syncthreads();
#pragma unroll
    for (int r = 0; r < 4; r++) {
      int ci = t + 256 * r;
      int row = ci >> 3, q = ci & 7;
      uint2 hi, lo;
      split_pack(regW[r], hi, lo);
      *(uint2*)(Whs + row * 80 + q * 8) = hi;
      *(uint2*)(Wls + row * 80 + q * 8) = lo;
      split_pack(regX[r], hi, lo);
      *(uint2*)(Xhs + row * 80 + q * 8) = hi;
      *(uint2*)(Xls + row * 80 + q * 8) = lo;
    }
    __syncthreads();

    if (kt + 32 < DIM) ISSUE_LOADS(kt + 32);

    const int c16 = (lane >> 4) * 16;
    const int rlo = lane & 15;
    short8 bh[4], bl[4];
#pragma unroll
    for (int j = 0; j < 4; j++) {
      int rowX = wc * 64 + j * 16 + rlo;
      bh[j] = *(const short8*)(Xhs + rowX * 80 + c16);
      bl[j] = *(const short8*)(Xls + rowX * 80 + c16);
    }
#pragma unroll
    for (int i = 0; i < 4; i++) {
      int rowW = wr * 64 + i * 16 + rlo;
      short8 ah = *(const short8*)(Whs + rowW * 80 + c16);
      short8 al = *(const short8*)(Wls + rowW * 80 + c16);
#pragma unroll
      for (int j = 0; j < 4; j++) {
        acc[i][j] = __builtin_amdgcn_mfma_f32_16x16x32_bf16(ah, bh[j], acc[i][j], 0, 0, 0);
        acc[i][j] = __builtin_amdgcn_mfma_f32_16x16x32_bf16(ah, bl[j], acc[i][j], 0, 0, 0);
        acc[i][j] = __builtin_amdgcn_mfma_f32_16x16x32_bf16(al, bh[j], acc[i][j], 0, 0, 0);
      }
    }
  }
#undef ISSUE_LOADS

#pragma unroll
  for (int i = 0; i < 4; i++) {
    int e0 = eTile + wr * 64 + i * 16 + (lane >> 4) * 4;
#pragma unroll
    for (int reg = 0; reg < 4; reg++) {
      int e = e0 + reg;
      float bb = bias[e];
      float* orow = proj + ((size_t)(b * DIM + e)) * SEQ + sTile + wc * 64;
#pragma unroll
      for (int j = 0; j < 4; j++)
        orow[j * 16 + (lane & 15)] = acc[i][j][reg] + bb;
    }
  }
}

// ---------------------------------------------------------------------------
// Evolve (unchanged from R16: best measured structure, 63.5-65 us, no spills).
// Block = 256 thr = 4 waves = 1 plane; wave w owns rows [16w,16w+16);
// lane = 4 rows x 4 cols (u[4][2] = 8 VGPR state, ~45 total -> fits the
// allocator's 64-VGPR/8-wave target). Boundary rows via 4 KB double-buffered
// LDS, one barrier/step. Pade[5/4]+Ac-fold tanh, shared rcp per 4 cells,
// DPP side halos with free edge zeroing, shfl-then-select (R4 lesson).
// ---------------------------------------------------------------------------
__global__ __launch_bounds__(256) void evolve_kernel(
    const float* __restrict__ proj, const float* __restrict__ dcoef,
    float* __restrict__ out) {
  const int tid   = threadIdx.x;
  const int w     = tid >> 6;
  const int lane  = tid & 63;
  const int plane = blockIdx.x;
  const int lx = lane & 15;
  const int ly = lane >> 4;

  __shared__ float bnd[2][4][2][64];
  __shared__ float psum[4];

  const float D   = dcoef[0];
  const float DDf = DT * D;
  const float Acf = 1.f - DT - 4.f * DDf;
  const float DDu = __uint_as_float(__builtin_amdgcn_readfirstlane(__float_as_uint(DDf)));
  const float Acu = __uint_as_float(__builtin_amdgcn_readfirstlane(__float_as_uint(Acf)));
  const float PAf = DT + 6.f * Acu;
  const float P0f = 15.f * (DT + Acu);
  const float P0u = __uint_as_float(__builtin_amdgcn_readfirstlane(__float_as_uint(P0f)));
  const f32x2 kDD  = {DDu, DDu};
  const f32x2 kP0  = {P0u, P0u};
  const f32x2 k15  = {15.f, 15.f};
  const f32x2 kPAv = {PAf, PAf};
  const f32x2 k6v  = {6.f, 6.f};

  const float* p = proj + (size_t)plane * (HW * HW)
                 + (size_t)(w * 16 + ly * 4) * HW + lx * 4;

  f32x2 u[4][2];
#pragma unroll
  for (int r = 0; r < 4; r++) {
    float4 v = *(const float4*)(p + r * HW);
    u[r][0] = f32x2{v.x, v.y};
    u[r][1] = f32x2{v.z, v.w};
  }

  auto pair2 = [&](f32x2 svA, f32x2 svB, f32x2 s4A, f32x2 s4B,
                   f32x2& zA, f32x2& zB) {
    f32x2 yA = pk_mul(svA, svA), yB = pk_mul(svB, svB);
    f32x2 tA = pk_fma_addk(yA, kPAv, kP0);
    f32x2 tB = pk_fma_addk(yB, kPAv, kP0);
    f32x2 nA = pk_mul(svA, tA);
    f32x2 nB = pk_mul(svB, tB);
    f32x2 dA = pk_fma_addk(yA, k6v, k15);
    f32x2 dB = pk_fma_addk(yB, k6v, k15);
    float pA = dA.x * dA.y, qB = dB.x * dB.y;
    float rr = __builtin_amdgcn_rcpf(pA * qB);
    float qr = qB * rr, pr = pA * rr;
    f32x2 iA; iA.x = dA.y * qr; iA.y = dA.x * qr;
    f32x2 iB; iB.x = dB.y * pr; iB.y = dB.x * pr;
    zA = pk_fma_s1(s4A, kDD, pk_mul(nA, iA));
    zB = pk_fma_s1(s4B, kDD, pk_mul(nB, iB));
  };

  if (ly == 0) {
    float4 pub; pub.x = u[0][0].x; pub.y = u[0][0].y;
    pub.z = u[0][1].x; pub.w = u[0][1].y;
    *(float4*)&bnd[0][w][0][lx * 4] = pub;
  }
  if (ly == 3) {
    float4 pub; pub.x = u[3][0].x; pub.y = u[3][0].y;
    pub.z = u[3][1].x; pub.w = u[3][1].y;
    *(float4*)&bnd[0][w][1][lx * 4] = pub;
  }
  __syncthreads();

  const int wup = (w > 0) ? w - 1 : 0;
  const int wdn = (w < 3) ? w + 1 : 3;

#pragma unroll 1
  for (int step = 0; step < NSTEP; step++) {
    const int rb = step & 1, wb = rb ^ 1;
    float4 nbt = *(const float4*)&bnd[rb][wup][1][lx * 4];
    float4 nbb = *(const float4*)&bnd[rb][wdn][0][lx * 4];

    float ax0 = __shfl(u[3][0].x, (lane - 16) & 63);
    float ay0 = __shfl(u[3][0].y, (lane - 16) & 63);
    float ax1 = __shfl(u[3][1].x, (lane - 16) & 63);
    float ay1 = __shfl(u[3][1].y, (lane - 16) & 63);
    f32x2 th0, th1;
    th0.x = (ly == 0) ? ((w > 0) ? nbt.x : 0.f) : ax0;
    th0.y = (ly == 0) ? ((w > 0) ? nbt.y : 0.f) : ay0;
    th1.x = (ly == 0) ? ((w > 0) ? nbt.z : 0.f) : ax1;
    th1.y = (ly == 0) ? ((w > 0) ? nbt.w : 0.f) : ay1;
    float bx0 = __shfl(u[0][0].x, (lane + 16) & 63);
    float by0 = __shfl(u[0][0].y, (lane + 16) & 63);
    float bx1 = __shfl(u[0][1].x, (lane + 16) & 63);
    float by1 = __shfl(u[0][1].y, (lane + 16) & 63);
    f32x2 bh0, bh1;
    bh0.x = (ly == 3) ? ((w < 3) ? nbb.x : 0.f) : bx0;
    bh0.y = (ly == 3) ? ((w < 3) ? nbb.y : 0.f) : by0;
    bh1.x = (ly == 3) ? ((w < 3) ? nbb.z : 0.f) : bx1;
    bh1.y = (ly == 3) ? ((w < 3) ? nbb.w : 0.f) : by1;

    f32x2 prev0 = th0, prev1 = th1;
#pragma unroll
    for (int r = 0; r < 4; r++) {
      f32x2 sv0 = u[r][0], sv1 = u[r][1];
      float lfv = dpp_from_left(sv1.y);
      float rtv = dpp_from_right(sv0.x);
      f32x2 dn0 = (r < 3) ? u[r + 1][0] : bh0;
      f32x2 dn1 = (r < 3) ? u[r + 1][1] : bh1;
      f32x2 hs0, hs1;
      hs0.x = lfv + sv0.y;   hs0.y = sv0.x + sv1.x;
      hs1.x = sv0.y + sv1.y; hs1.y = sv1.x + rtv;
      f32x2 s40 = pk_add(pk_add(prev0, dn0), hs0);
      f32x2 s41 = pk_add(pk_add(prev1, dn1), hs1);
      pair2(sv0, sv1, s40, s41, u[r][0], u[r][1]);
      prev0 = sv0; prev1 = sv1;
    }

    if (ly == 0) {
      float4 pub; pub.x = u[0][0].x; pub.y = u[0][0].y;
      pub.z = u[0][1].x; pub.w = u[0][1].y;
      *(float4*)&bnd[wb][w][0][lx * 4] = pub;
    }
    if (ly == 3) {
      float4 pub; pub.x = u[3][0].x; pub.y = u[3][0].y;
      pub.z = u[3][1].x; pub.w = u[3][1].y;
      *(float4*)&bnd[wb][w][1][lx * 4] = pub;
    }
    __syncthreads();
  }

  float s = 0.f;
#pragma unroll
  for (int r = 0; r < 4; r++)
#pragma unroll
    for (int q = 0; q < 2; q++) s += u[r][q].x + u[r][q].y;
#pragma unroll
  for (int off = 32; off > 0; off >>= 1) s += __shfl_xor(s, off);
  if (lane == 0) psum[w] = s;
  __syncthreads();
  if (w == 0 && lane == 0)
    out[plane] = (psum[0] + psum[1] + psum[2] + psum[3]) * (1.f / (HW * HW));
}

// ---------------------------------------------------------------------------
extern "C" void kernel_launch(void* const* d_in, const int* in_sizes, int n_in,
                              void* d_out, int out_size, void* d_ws, size_t ws_size,
                              hipStream_t stream) {
  const float* x    = (const float*)d_in[0];
  const float* W    = (const float*)d_in[1];
  const float* bias = (const float*)d_in[2];
  const float* dc   = (const float*)d_in[3];
  float* out  = (float*)d_out;
  float* proj = (float*)d_ws;   // BATCH*DIM*SEQ*4 = 64 MB

  dim3 g1(DIM / 128, SEQ / 128, BATCH);
  gemm_proj_mfma<<<g1, 256, 0, stream>>>(x, W, bias, proj);

  evolve_kernel<<<BATCH * DIM, 256, 0, stream>>>(proj, dc, out);
}

// Round 20
// 93.863 us; speedup vs baseline: 1.1488x; 1.0535x over previous
//
#include <hip/hip_runtime.h>
#include <stdint.h>

#define BATCH 16
#define SEQ   4096
#define DIM   256
#define HW    64
#define NSTEP 10
#define DT    0.3f

typedef __attribute__((ext_vector_type(8))) short short8;   // 8 bf16 in 4 VGPRs
typedef __attribute__((ext_vector_type(4))) float f32x4;
typedef __attribute__((ext_vector_type(2))) float f32x2;

// ---------------------------------------------------------------------------
// Packed-f32 VOP3P helpers (throughput-neutral vs scalar per R8).
// ---------------------------------------------------------------------------
__device__ __forceinline__ f32x2 pk_add(f32x2 a, f32x2 b) {
  f32x2 d; asm("v_pk_add_f32 %0, %1, %2" : "=v"(d) : "v"(a), "v"(b)); return d;
}
__device__ __forceinline__ f32x2 pk_mul(f32x2 a, f32x2 b) {
  f32x2 d; asm("v_pk_mul_f32 %0, %1, %2" : "=v"(d) : "v"(a), "v"(b)); return d;
}
__device__ __forceinline__ f32x2 pk_fma_addk(f32x2 a, f32x2 b, f32x2 ks) {
  f32x2 d; asm("v_pk_fma_f32 %0, %1, %2, %3" : "=v"(d) : "v"(a), "v"(b), "s"(ks)); return d;
}
__device__ __forceinline__ f32x2 pk_fma_s1(f32x2 a, f32x2 ks, f32x2 c) {
  f32x2 d; asm("v_pk_fma_f32 %0, %1, %2, %3" : "=v"(d) : "v"(a), "s"(ks), "v"(c)); return d;
}

// DPP lane shifts (16-lane rows align with plane edges; bound_ctrl zeroes).
__device__ __forceinline__ float dpp_from_left(float x) {
  return __int_as_float(__builtin_amdgcn_update_dpp(
      0, __float_as_int(x), 0x111, 0xF, 0xF, true));
}
__device__ __forceinline__ float dpp_from_right(float x) {
  return __int_as_float(__builtin_amdgcn_update_dpp(
      0, __float_as_int(x), 0x101, 0xF, 0xF, true));
}

// ---------------------------------------------------------------------------
// fp32 -> (bf16-hi, bf16-lo) split via TRUNCATE + v_perm pair-pack (R17).
// ---------------------------------------------------------------------------
__device__ __forceinline__ void split_pack(float4 v, uint2& hi, uint2& lo) {
  uint32_t u0 = __float_as_uint(v.x), u1 = __float_as_uint(v.y);
  uint32_t u2 = __float_as_uint(v.z), u3 = __float_as_uint(v.w);
  float h0 = __uint_as_float(u0 & 0xFFFF0000u);
  float h1 = __uint_as_float(u1 & 0xFFFF0000u);
  float h2 = __uint_as_float(u2 & 0xFFFF0000u);
  float h3 = __uint_as_float(u3 & 0xFFFF0000u);
  hi.x = __builtin_amdgcn_perm(u1, u0, 0x07060302u);
  hi.y = __builtin_amdgcn_perm(u3, u2, 0x07060302u);
  lo.x = __builtin_amdgcn_perm(__float_as_uint(v.y - h1),
                               __float_as_uint(v.x - h0), 0x07060302u);
  lo.y = __builtin_amdgcn_perm(__float_as_uint(v.w - h3),
                               __float_as_uint(v.z - h2), 0x07060302u);
}

// ---------------------------------------------------------------------------
// GEMM: proj[(b*DIM+e)*SEQ + s] = sum_d x[b,s,d]*W[e,d] + bias[e]
// bf16x3 emulated-fp32 MFMA (unchanged from R17).
// ---------------------------------------------------------------------------
__global__ __launch_bounds__(256) void gemm_proj_mfma(
    const float* __restrict__ x, const float* __restrict__ W,
    const float* __restrict__ bias, float* __restrict__ proj) {
  const int eTile = blockIdx.x * 128;
  const int sTile = blockIdx.y * 128;
  const int b     = blockIdx.z;
  const int t     = threadIdx.x;
  const int lane  = t & 63;
  const int wid   = t >> 6;
  const int wr    = wid >> 1;
  const int wc    = wid & 1;

  __shared__ char lds[4 * 128 * 80];
  char* Whs = lds;
  char* Wls = lds + 10240;
  char* Xhs = lds + 20480;
  char* Xls = lds + 30720;

  const float* xb = x + (size_t)b * SEQ * DIM;

  f32x4 acc[4][4] = {};
  float4 regW[4], regX[4];

#define ISSUE_LOADS(KT)                                                        \
  {                                                                            \
    _Pragma("unroll")                                                          \
    for (int r = 0; r < 4; r++) {                                              \
      int ci = t + 256 * r;                                                    \
      int row = ci >> 3, q = ci & 7;                                           \
      regW[r] = *(const float4*)(W  + (size_t)(eTile + row) * DIM + (KT) + q * 4); \
      regX[r] = *(const float4*)(xb + (size_t)(sTile + row) * DIM + (KT) + q * 4); \
    }                                                                          \
  }

  ISSUE_LOADS(0);

  for (int kt = 0; kt < DIM; kt += 32) {
    __syncthreads();
#pragma unroll
    for (int r = 0; r < 4; r++) {
      int ci = t + 256 * r;
      int row = ci >> 3, q = ci & 7;
      uint2 hi, lo;
      split_pack(regW[r], hi, lo);
      *(uint2*)(Whs + row * 80 + q * 8) = hi;
      *(uint2*)(Wls + row * 80 + q * 8) = lo;
      split_pack(regX[r], hi, lo);
      *(uint2*)(Xhs + row * 80 + q * 8) = hi;
      *(uint2*)(Xls + row * 80 + q * 8) = lo;
    }
    __syncthreads();

    if (kt + 32 < DIM) ISSUE_LOADS(kt + 32);

    const int c16 = (lane >> 4) * 16;
    const int rlo = lane & 15;
    short8 bh[4], bl[4];
#pragma unroll
    for (int j = 0; j < 4; j++) {
      int rowX = wc * 64 + j * 16 + rlo;
      bh[j] = *(const short8*)(Xhs + rowX * 80 + c16);
      bl[j] = *(const short8*)(Xls + rowX * 80 + c16);
    }
#pragma unroll
    for (int i = 0; i < 4; i++) {
      int rowW = wr * 64 + i * 16 + rlo;
      short8 ah = *(const short8*)(Whs + rowW * 80 + c16);
      short8 al = *(const short8*)(Wls + rowW * 80 + c16);
#pragma unroll
      for (int j = 0; j < 4; j++) {
        acc[i][j] = __builtin_amdgcn_mfma_f32_16x16x32_bf16(ah, bh[j], acc[i][j], 0, 0, 0);
        acc[i][j] = __builtin_amdgcn_mfma_f32_16x16x32_bf16(ah, bl[j], acc[i][j], 0, 0, 0);
        acc[i][j] = __builtin_amdgcn_mfma_f32_16x16x32_bf16(al, bh[j], acc[i][j], 0, 0, 0);
      }
    }
  }
#undef ISSUE_LOADS

#pragma unroll
  for (int i = 0; i < 4; i++) {
    int e0 = eTile + wr * 64 + i * 16 + (lane >> 4) * 4;
#pragma unroll
    for (int reg = 0; reg < 4; reg++) {
      int e = e0 + reg;
      float bb = bias[e];
      float* orow = proj + ((size_t)(b * DIM + e)) * SEQ + sTile + wc * 64;
#pragma unroll
      for (int j = 0; j < 4; j++)
        orow[j * 16 + (lane & 15)] = acc[i][j][reg] + bb;
    }
  }
}

// ---------------------------------------------------------------------------
// Evolve (R18): ALL vertical halos through an LDS boundary-row table ->
// ZERO shfls, ZERO selects, ZERO divergent publishes.
// Block = 256 thr = 4 waves = 1 plane; lane block (w,ly) owns rows
// [g, g+4), g = 16w+4ly, cols [4lx, 4lx+4). Table bnd[2][34][64]:
// rows r%4==0 at slot r/2+1, rows r%4==3 at slot (r+1)/2, plus zero
// SENTINEL slots 0 (row -1) and 33 (row 64). For block base = 8w+2ly:
//   top halo (row g-1)  = slot base    (sentinel when g==0)
//   bot halo (row g+4)  = slot base+3  (sentinel when g==60)
//   publish row g  -> slot base+1 ; row g+3 -> slot base+2
// All lanes read/write unconditionally; plane edges hit the zero sentinels.
// Double-buffered, end-of-step publish, 1 barrier/step (R11-proven ordering).
// Pade[5/4]+Ac-fold tanh, shared rcp per 4 cells, DPP side halos (free edge
// zeroing). u[4][2] = 8 VGPR state -> fits the 64-VGPR/8-wave target.
// ---------------------------------------------------------------------------
__global__ __launch_bounds__(256) void evolve_kernel(
    const float* __restrict__ proj, const float* __restrict__ dcoef,
    float* __restrict__ out) {
  const int tid   = threadIdx.x;
  const int w     = tid >> 6;
  const int lane  = tid & 63;
  const int plane = blockIdx.x;
  const int lx = lane & 15;
  const int ly = lane >> 4;

  __shared__ float bnd[2][34][64];   // 17408 B
  __shared__ float psum[4];

  const float D   = dcoef[0];
  const float DDf = DT * D;
  const float Acf = 1.f - DT - 4.f * DDf;
  const float DDu = __uint_as_float(__builtin_amdgcn_readfirstlane(__float_as_uint(DDf)));
  const float Acu = __uint_as_float(__builtin_amdgcn_readfirstlane(__float_as_uint(Acf)));
  // Pade[5/4] fold: P(y) = (DT + 6*Ac)*y + 15*(DT + Ac);  Dn(y) = 6y + 15
  const float PAf = DT + 6.f * Acu;
  const float P0f = 15.f * (DT + Acu);
  const float P0u = __uint_as_float(__builtin_amdgcn_readfirstlane(__float_as_uint(P0f)));
  const f32x2 kDD  = {DDu, DDu};
  const f32x2 kP0  = {P0u, P0u};
  const f32x2 k15  = {15.f, 15.f};
  const f32x2 kPAv = {PAf, PAf};
  const f32x2 k6v  = {6.f, 6.f};

  const float* p = proj + (size_t)plane * (HW * HW)
                 + (size_t)(w * 16 + ly * 4) * HW + lx * 4;

  f32x2 u[4][2];
#pragma unroll
  for (int r = 0; r < 4; r++) {
    float4 v = *(const float4*)(p + r * HW);
    u[r][0] = f32x2{v.x, v.y};
    u[r][1] = f32x2{v.z, v.w};
  }

  auto pair2 = [&](f32x2 svA, f32x2 svB, f32x2 s4A, f32x2 s4B,
                   f32x2& zA, f32x2& zB) {
    f32x2 yA = pk_mul(svA, svA), yB = pk_mul(svB, svB);
    f32x2 tA = pk_fma_addk(yA, kPAv, kP0);
    f32x2 tB = pk_fma_addk(yB, kPAv, kP0);
    f32x2 nA = pk_mul(svA, tA);
    f32x2 nB = pk_mul(svB, tB);
    f32x2 dA = pk_fma_addk(yA, k6v, k15);
    f32x2 dB = pk_fma_addk(yB, k6v, k15);
    float pA = dA.x * dA.y, qB = dB.x * dB.y;
    float rr = __builtin_amdgcn_rcpf(pA * qB);
    float qr = qB * rr, pr = pA * rr;
    f32x2 iA; iA.x = dA.y * qr; iA.y = dA.x * qr;
    f32x2 iB; iB.x = dB.y * pr; iB.y = dB.x * pr;
    zA = pk_fma_s1(s4A, kDD, pk_mul(nA, iA));
    zB = pk_fma_s1(s4B, kDD, pk_mul(nB, iB));
  };

  const int base = w * 8 + ly * 2;

  // prologue: zero sentinels (slots 0 & 33, both buffers) + publish OLD rows
  {
    int bsel = tid >> 7;            // 0..1
    int ssel = (tid >> 6) & 1;      // 0..1
    bnd[bsel][ssel * 33][lane] = 0.f;
  }
  {
    float4 pub0; pub0.x = u[0][0].x; pub0.y = u[0][0].y;
    pub0.z = u[0][1].x; pub0.w = u[0][1].y;
    *(float4*)&bnd[0][base + 1][lx * 4] = pub0;
    float4 pub3; pub3.x = u[3][0].x; pub3.y = u[3][0].y;
    pub3.z = u[3][1].x; pub3.w = u[3][1].y;
    *(float4*)&bnd[0][base + 2][lx * 4] = pub3;
  }
  __syncthreads();

#pragma unroll 1
  for (int step = 0; step < NSTEP; step++) {
    const int rb = step & 1, wb = rb ^ 1;
    // vertical halos: unconditional LDS reads (sentinels give plane edges)
    float4 thv = *(const float4*)&bnd[rb][base][lx * 4];
    float4 bhv = *(const float4*)&bnd[rb][base + 3][lx * 4];
    f32x2 th0 = {thv.x, thv.y}, th1 = {thv.z, thv.w};
    f32x2 bh0 = {bhv.x, bhv.y}, bh1 = {bhv.z, bhv.w};

    // rows 0..3 in order, in place, rolling prev; side halos JIT via DPP
    f32x2 prev0 = th0, prev1 = th1;
#pragma unroll
    for (int r = 0; r < 4; r++) {
      f32x2 sv0 = u[r][0], sv1 = u[r][1];
      float lfv = dpp_from_left(sv1.y);
      float rtv = dpp_from_right(sv0.x);
      f32x2 dn0 = (r < 3) ? u[r + 1][0] : bh0;
      f32x2 dn1 = (r < 3) ? u[r + 1][1] : bh1;
      f32x2 hs0, hs1;
      hs0.x = lfv + sv0.y;   hs0.y = sv0.x + sv1.x;
      hs1.x = sv0.y + sv1.y; hs1.y = sv1.x + rtv;
      f32x2 s40 = pk_add(pk_add(prev0, dn0), hs0);
      f32x2 s41 = pk_add(pk_add(prev1, dn1), hs1);
      pair2(sv0, sv1, s40, s41, u[r][0], u[r][1]);
      prev0 = sv0; prev1 = sv1;
    }

    // publish NEW boundary rows (all lanes, unconditional)
    float4 pub0; pub0.x = u[0][0].x; pub0.y = u[0][0].y;
    pub0.z = u[0][1].x; pub0.w = u[0][1].y;
    *(float4*)&bnd[wb][base + 1][lx * 4] = pub0;
    float4 pub3; pub3.x = u[3][0].x; pub3.y = u[3][0].y;
    pub3.z = u[3][1].x; pub3.w = u[3][1].y;
    *(float4*)&bnd[wb][base + 2][lx * 4] = pub3;
    __syncthreads();   // one barrier per step
  }

  // spatial mean: wave-reduce 16 cells, combine 4 waves via LDS
  float s = 0.f;
#pragma unroll
  for (int r = 0; r < 4; r++)
#pragma unroll
    for (int q = 0; q < 2; q++) s += u[r][q].x + u[r][q].y;
#pragma unroll
  for (int off = 32; off > 0; off >>= 1) s += __shfl_xor(s, off);
  if (lane == 0) psum[w] = s;
  __syncthreads();
  if (w == 0 && lane == 0)
    out[plane] = (psum[0] + psum[1] + psum[2] + psum[3]) * (1.f / (HW * HW));
}

// ---------------------------------------------------------------------------
extern "C" void kernel_launch(void* const* d_in, const int* in_sizes, int n_in,
                              void* d_out, int out_size, void* d_ws, size_t ws_size,
                              hipStream_t stream) {
  const float* x    = (const float*)d_in[0];
  const float* W    = (const float*)d_in[1];
  const float* bias = (const float*)d_in[2];
  const float* dc   = (const float*)d_in[3];
  float* out  = (float*)d_out;
  float* proj = (float*)d_ws;   // BATCH*DIM*SEQ*4 = 64 MB

  dim3 g1(DIM / 128, SEQ / 128, BATCH);
  gemm_proj_mfma<<<g1, 256, 0, stream>>>(x, W, bias, proj);

  evolve_kernel<<<BATCH * DIM, 256, 0, stream>>>(proj, dc, out);
}

// Round 21
// 89.955 us; speedup vs baseline: 1.1987x; 1.0434x over previous
//
#include <hip/hip_runtime.h>
#include <stdint.h>

#define BATCH 16
#define SEQ   4096
#define DIM   256
#define HW    64
#define NSTEP 10
#define DT    0.3f

typedef __attribute__((ext_vector_type(8))) short short8;   // 8 bf16 in 4 VGPRs
typedef __attribute__((ext_vector_type(4))) float f32x4;
typedef __attribute__((ext_vector_type(2))) float f32x2;

// ---------------------------------------------------------------------------
// Packed-f32 VOP3P helpers (throughput-neutral vs scalar per R8).
// ---------------------------------------------------------------------------
__device__ __forceinline__ f32x2 pk_add(f32x2 a, f32x2 b) {
  f32x2 d; asm("v_pk_add_f32 %0, %1, %2" : "=v"(d) : "v"(a), "v"(b)); return d;
}
__device__ __forceinline__ f32x2 pk_mul(f32x2 a, f32x2 b) {
  f32x2 d; asm("v_pk_mul_f32 %0, %1, %2" : "=v"(d) : "v"(a), "v"(b)); return d;
}
__device__ __forceinline__ f32x2 pk_fma_addk(f32x2 a, f32x2 b, f32x2 ks) {
  f32x2 d; asm("v_pk_fma_f32 %0, %1, %2, %3" : "=v"(d) : "v"(a), "v"(b), "s"(ks)); return d;
}
__device__ __forceinline__ f32x2 pk_fma_s1(f32x2 a, f32x2 ks, f32x2 c) {
  f32x2 d; asm("v_pk_fma_f32 %0, %1, %2, %3" : "=v"(d) : "v"(a), "s"(ks), "v"(c)); return d;
}

// DPP lane shifts (16-lane rows align with plane edges; bound_ctrl zeroes).
__device__ __forceinline__ float dpp_from_left(float x) {
  return __int_as_float(__builtin_amdgcn_update_dpp(
      0, __float_as_int(x), 0x111, 0xF, 0xF, true));
}
__device__ __forceinline__ float dpp_from_right(float x) {
  return __int_as_float(__builtin_amdgcn_update_dpp(
      0, __float_as_int(x), 0x101, 0xF, 0xF, true));
}

// ---------------------------------------------------------------------------
// W path: fp32 -> (bf16-hi, bf16-lo) split via TRUNCATE + v_perm (R17).
// ---------------------------------------------------------------------------
__device__ __forceinline__ void split_pack(float4 v, uint2& hi, uint2& lo) {
  uint32_t u0 = __float_as_uint(v.x), u1 = __float_as_uint(v.y);
  uint32_t u2 = __float_as_uint(v.z), u3 = __float_as_uint(v.w);
  float h0 = __uint_as_float(u0 & 0xFFFF0000u);
  float h1 = __uint_as_float(u1 & 0xFFFF0000u);
  float h2 = __uint_as_float(u2 & 0xFFFF0000u);
  float h3 = __uint_as_float(u3 & 0xFFFF0000u);
  hi.x = __builtin_amdgcn_perm(u1, u0, 0x07060302u);
  hi.y = __builtin_amdgcn_perm(u3, u2, 0x07060302u);
  lo.x = __builtin_amdgcn_perm(__float_as_uint(v.y - h1),
                               __float_as_uint(v.x - h0), 0x07060302u);
  lo.y = __builtin_amdgcn_perm(__float_as_uint(v.w - h3),
                               __float_as_uint(v.z - h2), 0x07060302u);
}

// ---------------------------------------------------------------------------
// X path (R21): round-to-nearest-even bf16, HI ONLY. The x-lo term is
// dropped from the MFMA sum: proj = sum (wh+wl)*xh = sum w*xh; error
// sum w*xl has std ~9e-4/cell (RNE |xl|~2^-9|x|), ~1.4e-5 after the
// 4096-cell spatial mean -> negligible vs Pade's 2.4e-4. Kills 1/3 of the
// MFMAs, half the X staging VALU, 1 LDS store + 4 frag loads per K-tile.
// ---------------------------------------------------------------------------
__device__ __forceinline__ uint2 pack_hi_rne(float4 v) {
  uint32_t u0 = __float_as_uint(v.x); u0 += 0x7FFFu + ((u0 >> 16) & 1u);
  uint32_t u1 = __float_as_uint(v.y); u1 += 0x7FFFu + ((u1 >> 16) & 1u);
  uint32_t u2 = __float_as_uint(v.z); u2 += 0x7FFFu + ((u2 >> 16) & 1u);
  uint32_t u3 = __float_as_uint(v.w); u3 += 0x7FFFu + ((u3 >> 16) & 1u);
  uint2 hi;
  hi.x = __builtin_amdgcn_perm(u1, u0, 0x07060302u);
  hi.y = __builtin_amdgcn_perm(u3, u2, 0x07060302u);
  return hi;
}

// ---------------------------------------------------------------------------
// GEMM: proj[(b*DIM+e)*SEQ + s] = sum_d x[b,s,d]*W[e,d] + bias[e]
// bf16x2(W) x bf16(X) emulated-fp32 MFMA: 2 MFMA per fragment pair.
// ---------------------------------------------------------------------------
__global__ __launch_bounds__(256) void gemm_proj_mfma(
    const float* __restrict__ x, const float* __restrict__ W,
    const float* __restrict__ bias, float* __restrict__ proj) {
  const int eTile = blockIdx.x * 128;
  const int sTile = blockIdx.y * 128;
  const int b     = blockIdx.z;
  const int t     = threadIdx.x;
  const int lane  = t & 63;
  const int wid   = t >> 6;
  const int wr    = wid >> 1;
  const int wc    = wid & 1;

  __shared__ char lds[3 * 128 * 80];   // Whs, Wls, Xhs
  char* Whs = lds;
  char* Wls = lds + 10240;
  char* Xhs = lds + 20480;

  const float* xb = x + (size_t)b * SEQ * DIM;

  f32x4 acc[4][4] = {};
  float4 regW[4], regX[4];

#define ISSUE_LOADS(KT)                                                        \
  {                                                                            \
    _Pragma("unroll")                                                          \
    for (int r = 0; r < 4; r++) {                                              \
      int ci = t + 256 * r;                                                    \
      int row = ci >> 3, q = ci & 7;                                           \
      regW[r] = *(const float4*)(W  + (size_t)(eTile + row) * DIM + (KT) + q * 4); \
      regX[r] = *(const float4*)(xb + (size_t)(sTile + row) * DIM + (KT) + q * 4); \
    }                                                                          \
  }

  ISSUE_LOADS(0);

  for (int kt = 0; kt < DIM; kt += 32) {
    __syncthreads();
#pragma unroll
    for (int r = 0; r < 4; r++) {
      int ci = t + 256 * r;
      int row = ci >> 3, q = ci & 7;
      uint2 hi, lo;
      split_pack(regW[r], hi, lo);
      *(uint2*)(Whs + row * 80 + q * 8) = hi;
      *(uint2*)(Wls + row * 80 + q * 8) = lo;
      *(uint2*)(Xhs + row * 80 + q * 8) = pack_hi_rne(regX[r]);
    }
    __syncthreads();

    if (kt + 32 < DIM) ISSUE_LOADS(kt + 32);

    const int c16 = (lane >> 4) * 16;
    const int rlo = lane & 15;
    short8 bh[4];
#pragma unroll
    for (int j = 0; j < 4; j++) {
      int rowX = wc * 64 + j * 16 + rlo;
      bh[j] = *(const short8*)(Xhs + rowX * 80 + c16);
    }
#pragma unroll
    for (int i = 0; i < 4; i++) {
      int rowW = wr * 64 + i * 16 + rlo;
      short8 ah = *(const short8*)(Whs + rowW * 80 + c16);
      short8 al = *(const short8*)(Wls + rowW * 80 + c16);
#pragma unroll
      for (int j = 0; j < 4; j++) {
        acc[i][j] = __builtin_amdgcn_mfma_f32_16x16x32_bf16(ah, bh[j], acc[i][j], 0, 0, 0);
        acc[i][j] = __builtin_amdgcn_mfma_f32_16x16x32_bf16(al, bh[j], acc[i][j], 0, 0, 0);
      }
    }
  }
#undef ISSUE_LOADS

#pragma unroll
  for (int i = 0; i < 4; i++) {
    int e0 = eTile + wr * 64 + i * 16 + (lane >> 4) * 4;
#pragma unroll
    for (int reg = 0; reg < 4; reg++) {
      int e = e0 + reg;
      float bb = bias[e];
      float* orow = proj + ((size_t)(b * DIM + e)) * SEQ + sTile + wc * 64;
#pragma unroll
      for (int j = 0; j < 4; j++)
        orow[j * 16 + (lane & 15)] = acc[i][j][reg] + bb;
    }
  }
}

// ---------------------------------------------------------------------------
// Evolve (unchanged from R20: 59 us, VGPR 24, zero conflicts, WRITE 128 B).
// All vertical halos via double-buffered LDS boundary-row table with zero
// sentinels -> zero shfls/selects/divergent publishes. Pade[5/4]+Ac-fold
// tanh, shared rcp per 4 cells, DPP side halos. 1 barrier/step.
// ---------------------------------------------------------------------------
__global__ __launch_bounds__(256) void evolve_kernel(
    const float* __restrict__ proj, const float* __restrict__ dcoef,
    float* __restrict__ out) {
  const int tid   = threadIdx.x;
  const int w     = tid >> 6;
  const int lane  = tid & 63;
  const int plane = blockIdx.x;
  const int lx = lane & 15;
  const int ly = lane >> 4;

  __shared__ float bnd[2][34][64];   // 17408 B
  __shared__ float psum[4];

  const float D   = dcoef[0];
  const float DDf = DT * D;
  const float Acf = 1.f - DT - 4.f * DDf;
  const float DDu = __uint_as_float(__builtin_amdgcn_readfirstlane(__float_as_uint(DDf)));
  const float Acu = __uint_as_float(__builtin_amdgcn_readfirstlane(__float_as_uint(Acf)));
  const float PAf = DT + 6.f * Acu;
  const float P0f = 15.f * (DT + Acu);
  const float P0u = __uint_as_float(__builtin_amdgcn_readfirstlane(__float_as_uint(P0f)));
  const f32x2 kDD  = {DDu, DDu};
  const f32x2 kP0  = {P0u, P0u};
  const f32x2 k15  = {15.f, 15.f};
  const f32x2 kPAv = {PAf, PAf};
  const f32x2 k6v  = {6.f, 6.f};

  const float* p = proj + (size_t)plane * (HW * HW)
                 + (size_t)(w * 16 + ly * 4) * HW + lx * 4;

  f32x2 u[4][2];
#pragma unroll
  for (int r = 0; r < 4; r++) {
    float4 v = *(const float4*)(p + r * HW);
    u[r][0] = f32x2{v.x, v.y};
    u[r][1] = f32x2{v.z, v.w};
  }

  auto pair2 = [&](f32x2 svA, f32x2 svB, f32x2 s4A, f32x2 s4B,
                   f32x2& zA, f32x2& zB) {
    f32x2 yA = pk_mul(svA, svA), yB = pk_mul(svB, svB);
    f32x2 tA = pk_fma_addk(yA, kPAv, kP0);
    f32x2 tB = pk_fma_addk(yB, kPAv, kP0);
    f32x2 nA = pk_mul(svA, tA);
    f32x2 nB = pk_mul(svB, tB);
    f32x2 dA = pk_fma_addk(yA, k6v, k15);
    f32x2 dB = pk_fma_addk(yB, k6v, k15);
    float pA = dA.x * dA.y, qB = dB.x * dB.y;
    float rr = __builtin_amdgcn_rcpf(pA * qB);
    float qr = qB * rr, pr = pA * rr;
    f32x2 iA; iA.x = dA.y * qr; iA.y = dA.x * qr;
    f32x2 iB; iB.x = dB.y * pr; iB.y = dB.x * pr;
    zA = pk_fma_s1(s4A, kDD, pk_mul(nA, iA));
    zB = pk_fma_s1(s4B, kDD, pk_mul(nB, iB));
  };

  const int base = w * 8 + ly * 2;

  // prologue: zero sentinels (slots 0 & 33, both buffers) + publish OLD rows
  {
    int bsel = tid >> 7;
    int ssel = (tid >> 6) & 1;
    bnd[bsel][ssel * 33][lane] = 0.f;
  }
  {
    float4 pub0; pub0.x = u[0][0].x; pub0.y = u[0][0].y;
    pub0.z = u[0][1].x; pub0.w = u[0][1].y;
    *(float4*)&bnd[0][base + 1][lx * 4] = pub0;
    float4 pub3; pub3.x = u[3][0].x; pub3.y = u[3][0].y;
    pub3.z = u[3][1].x; pub3.w = u[3][1].y;
    *(float4*)&bnd[0][base + 2][lx * 4] = pub3;
  }
  __syncthreads();

#pragma unroll 1
  for (int step = 0; step < NSTEP; step++) {
    const int rb = step & 1, wb = rb ^ 1;
    float4 thv = *(const float4*)&bnd[rb][base][lx * 4];
    float4 bhv = *(const float4*)&bnd[rb][base + 3][lx * 4];
    f32x2 th0 = {thv.x, thv.y}, th1 = {thv.z, thv.w};
    f32x2 bh0 = {bhv.x, bhv.y}, bh1 = {bhv.z, bhv.w};

    f32x2 prev0 = th0, prev1 = th1;
#pragma unroll
    for (int r = 0; r < 4; r++) {
      f32x2 sv0 = u[r][0], sv1 = u[r][1];
      float lfv = dpp_from_left(sv1.y);
      float rtv = dpp_from_right(sv0.x);
      f32x2 dn0 = (r < 3) ? u[r + 1][0] : bh0;
      f32x2 dn1 = (r < 3) ? u[r + 1][1] : bh1;
      f32x2 hs0, hs1;
      hs0.x = lfv + sv0.y;   hs0.y = sv0.x + sv1.x;
      hs1.x = sv0.y + sv1.y; hs1.y = sv1.x + rtv;
      f32x2 s40 = pk_add(pk_add(prev0, dn0), hs0);
      f32x2 s41 = pk_add(pk_add(prev1, dn1), hs1);
      pair2(sv0, sv1, s40, s41, u[r][0], u[r][1]);
      prev0 = sv0; prev1 = sv1;
    }

    float4 pub0; pub0.x = u[0][0].x; pub0.y = u[0][0].y;
    pub0.z = u[0][1].x; pub0.w = u[0][1].y;
    *(float4*)&bnd[wb][base + 1][lx * 4] = pub0;
    float4 pub3; pub3.x = u[3][0].x; pub3.y = u[3][0].y;
    pub3.z = u[3][1].x; pub3.w = u[3][1].y;
    *(float4*)&bnd[wb][base + 2][lx * 4] = pub3;
    __syncthreads();
  }

  float s = 0.f;
#pragma unroll
  for (int r = 0; r < 4; r++)
#pragma unroll
    for (int q = 0; q < 2; q++) s += u[r][q].x + u[r][q].y;
#pragma unroll
  for (int off = 32; off > 0; off >>= 1) s += __shfl_xor(s, off);
  if (lane == 0) psum[w] = s;
  __syncthreads();
  if (w == 0 && lane == 0)
    out[plane] = (psum[0] + psum[1] + psum[2] + psum[3]) * (1.f / (HW * HW));
}

// ---------------------------------------------------------------------------
extern "C" void kernel_launch(void* const* d_in, const int* in_sizes, int n_in,
                              void* d_out, int out_size, void* d_ws, size_t ws_size,
                              hipStream_t stream) {
  const float* x    = (const float*)d_in[0];
  const float* W    = (const float*)d_in[1];
  const float* bias = (const float*)d_in[2];
  const float* dc   = (const float*)d_in[3];
  float* out  = (float*)d_out;
  float* proj = (float*)d_ws;   // BATCH*DIM*SEQ*4 = 64 MB

  dim3 g1(DIM / 128, SEQ / 128, BATCH);
  gemm_proj_mfma<<<g1, 256, 0, stream>>>(x, W, bias, proj);

  evolve_kernel<<<BATCH * DIM, 256, 0, stream>>>(proj, dc, out);
}

// Round 22
// 82.295 us; speedup vs baseline: 1.3103x; 1.0931x over previous
//
#include <hip/hip_runtime.h>
#include <stdint.h>

#define BATCH 16
#define SEQ   4096
#define DIM   256
#define HW    64
#define NSTEP 10
#define DT    0.3f

typedef __attribute__((ext_vector_type(8))) short short8;   // 8 bf16 in 4 VGPRs
typedef __attribute__((ext_vector_type(4))) float f32x4;
typedef __attribute__((ext_vector_type(2))) float f32x2;

// ---------------------------------------------------------------------------
// Packed-f32 VOP3P helpers (throughput-neutral vs scalar per R8).
// ---------------------------------------------------------------------------
__device__ __forceinline__ f32x2 pk_add(f32x2 a, f32x2 b) {
  f32x2 d; asm("v_pk_add_f32 %0, %1, %2" : "=v"(d) : "v"(a), "v"(b)); return d;
}
__device__ __forceinline__ f32x2 pk_mul(f32x2 a, f32x2 b) {
  f32x2 d; asm("v_pk_mul_f32 %0, %1, %2" : "=v"(d) : "v"(a), "v"(b)); return d;
}
__device__ __forceinline__ f32x2 pk_fma_addk(f32x2 a, f32x2 b, f32x2 ks) {
  f32x2 d; asm("v_pk_fma_f32 %0, %1, %2, %3" : "=v"(d) : "v"(a), "v"(b), "s"(ks)); return d;
}
__device__ __forceinline__ f32x2 pk_fma_s1(f32x2 a, f32x2 ks, f32x2 c) {
  f32x2 d; asm("v_pk_fma_f32 %0, %1, %2, %3" : "=v"(d) : "v"(a), "s"(ks), "v"(c)); return d;
}

// DPP lane shifts (16-lane rows align with plane edges; bound_ctrl zeroes).
__device__ __forceinline__ float dpp_from_left(float x) {
  return __int_as_float(__builtin_amdgcn_update_dpp(
      0, __float_as_int(x), 0x111, 0xF, 0xF, true));
}
__device__ __forceinline__ float dpp_from_right(float x) {
  return __int_as_float(__builtin_amdgcn_update_dpp(
      0, __float_as_int(x), 0x101, 0xF, 0xF, true));
}

// ---------------------------------------------------------------------------
// W path: fp32 -> (bf16-hi, bf16-lo) split via TRUNCATE + v_perm (R17).
// ---------------------------------------------------------------------------
__device__ __forceinline__ void split_pack(float4 v, uint2& hi, uint2& lo) {
  uint32_t u0 = __float_as_uint(v.x), u1 = __float_as_uint(v.y);
  uint32_t u2 = __float_as_uint(v.z), u3 = __float_as_uint(v.w);
  float h0 = __uint_as_float(u0 & 0xFFFF0000u);
  float h1 = __uint_as_float(u1 & 0xFFFF0000u);
  float h2 = __uint_as_float(u2 & 0xFFFF0000u);
  float h3 = __uint_as_float(u3 & 0xFFFF0000u);
  hi.x = __builtin_amdgcn_perm(u1, u0, 0x07060302u);
  hi.y = __builtin_amdgcn_perm(u3, u2, 0x07060302u);
  lo.x = __builtin_amdgcn_perm(__float_as_uint(v.y - h1),
                               __float_as_uint(v.x - h0), 0x07060302u);
  lo.y = __builtin_amdgcn_perm(__float_as_uint(v.w - h3),
                               __float_as_uint(v.z - h2), 0x07060302u);
}

// X path: round-to-nearest-even bf16, HI ONLY (R21, verified: absmax
// unchanged — dropped x-lo term is noise-level after spatial mean).
__device__ __forceinline__ uint2 pack_hi_rne(float4 v) {
  uint32_t u0 = __float_as_uint(v.x); u0 += 0x7FFFu + ((u0 >> 16) & 1u);
  uint32_t u1 = __float_as_uint(v.y); u1 += 0x7FFFu + ((u1 >> 16) & 1u);
  uint32_t u2 = __float_as_uint(v.z); u2 += 0x7FFFu + ((u2 >> 16) & 1u);
  uint32_t u3 = __float_as_uint(v.w); u3 += 0x7FFFu + ((u3 >> 16) & 1u);
  uint2 hi;
  hi.x = __builtin_amdgcn_perm(u1, u0, 0x07060302u);
  hi.y = __builtin_amdgcn_perm(u3, u2, 0x07060302u);
  return hi;
}

// ---------------------------------------------------------------------------
// GEMM: proj[(b*DIM+e)*SEQ + s] = bf16( sum_d x[b,s,d]*W[e,d] + bias[e] )
// bf16x2(W) x bf16(X) emulated-fp32 MFMA. R22: proj stored as bf16 RNE —
// halves the intermediate's write (gemm) and read (evolve) HBM traffic.
// IC quantization ~1e-3/cell, independent -> ~1.6e-5 after the 4096-cell
// spatial mean; negligible vs Pade's 2.44e-4 (threshold 7.57e-4).
// ---------------------------------------------------------------------------
__global__ __launch_bounds__(256) void gemm_proj_mfma(
    const float* __restrict__ x, const float* __restrict__ W,
    const float* __restrict__ bias, ushort* __restrict__ proj) {
  const int eTile = blockIdx.x * 128;
  const int sTile = blockIdx.y * 128;
  const int b     = blockIdx.z;
  const int t     = threadIdx.x;
  const int lane  = t & 63;
  const int wid   = t >> 6;
  const int wr    = wid >> 1;
  const int wc    = wid & 1;

  __shared__ char lds[3 * 128 * 80];   // Whs, Wls, Xhs
  char* Whs = lds;
  char* Wls = lds + 10240;
  char* Xhs = lds + 20480;

  const float* xb = x + (size_t)b * SEQ * DIM;

  f32x4 acc[4][4] = {};
  float4 regW[4], regX[4];

#define ISSUE_LOADS(KT)                                                        \
  {                                                                            \
    _Pragma("unroll")                                                          \
    for (int r = 0; r < 4; r++) {                                              \
      int ci = t + 256 * r;                                                    \
      int row = ci >> 3, q = ci & 7;                                           \
      regW[r] = *(const float4*)(W  + (size_t)(eTile + row) * DIM + (KT) + q * 4); \
      regX[r] = *(const float4*)(xb + (size_t)(sTile + row) * DIM + (KT) + q * 4); \
    }                                                                          \
  }

  ISSUE_LOADS(0);

  for (int kt = 0; kt < DIM; kt += 32) {
    __syncthreads();
#pragma unroll
    for (int r = 0; r < 4; r++) {
      int ci = t + 256 * r;
      int row = ci >> 3, q = ci & 7;
      uint2 hi, lo;
      split_pack(regW[r], hi, lo);
      *(uint2*)(Whs + row * 80 + q * 8) = hi;
      *(uint2*)(Wls + row * 80 + q * 8) = lo;
      *(uint2*)(Xhs + row * 80 + q * 8) = pack_hi_rne(regX[r]);
    }
    __syncthreads();

    if (kt + 32 < DIM) ISSUE_LOADS(kt + 32);

    const int c16 = (lane >> 4) * 16;
    const int rlo = lane & 15;
    short8 bh[4];
#pragma unroll
    for (int j = 0; j < 4; j++) {
      int rowX = wc * 64 + j * 16 + rlo;
      bh[j] = *(const short8*)(Xhs + rowX * 80 + c16);
    }
#pragma unroll
    for (int i = 0; i < 4; i++) {
      int rowW = wr * 64 + i * 16 + rlo;
      short8 ah = *(const short8*)(Whs + rowW * 80 + c16);
      short8 al = *(const short8*)(Wls + rowW * 80 + c16);
#pragma unroll
      for (int j = 0; j < 4; j++) {
        acc[i][j] = __builtin_amdgcn_mfma_f32_16x16x32_bf16(ah, bh[j], acc[i][j], 0, 0, 0);
        acc[i][j] = __builtin_amdgcn_mfma_f32_16x16x32_bf16(al, bh[j], acc[i][j], 0, 0, 0);
      }
    }
  }
#undef ISSUE_LOADS

#pragma unroll
  for (int i = 0; i < 4; i++) {
    int e0 = eTile + wr * 64 + i * 16 + (lane >> 4) * 4;
#pragma unroll
    for (int reg = 0; reg < 4; reg++) {
      int e = e0 + reg;
      float bb = bias[e];
      ushort* orow = proj + ((size_t)(b * DIM + e)) * SEQ + sTile + wc * 64;
#pragma unroll
      for (int j = 0; j < 4; j++) {
        uint32_t uv = __float_as_uint(acc[i][j][reg] + bb);
        uv += 0x7FFFu + ((uv >> 16) & 1u);
        orow[j * 16 + (lane & 15)] = (ushort)(uv >> 16);
      }
    }
  }
}

// ---------------------------------------------------------------------------
// Evolve (R20 structure; R22: reads bf16 proj). All vertical halos via the
// double-buffered LDS boundary-row table with zero sentinels (zero shfls /
// selects / divergent publishes). Pade[5/4]+Ac-fold tanh, shared rcp per
// 4 cells, DPP side halos. 1 barrier/step. VGPR 24, zero bank conflicts.
// ---------------------------------------------------------------------------
__global__ __launch_bounds__(256) void evolve_kernel(
    const ushort* __restrict__ proj, const float* __restrict__ dcoef,
    float* __restrict__ out) {
  const int tid   = threadIdx.x;
  const int w     = tid >> 6;
  const int lane  = tid & 63;
  const int plane = blockIdx.x;
  const int lx = lane & 15;
  const int ly = lane >> 4;

  __shared__ float bnd[2][34][64];   // 17408 B
  __shared__ float psum[4];

  const float D   = dcoef[0];
  const float DDf = DT * D;
  const float Acf = 1.f - DT - 4.f * DDf;
  const float DDu = __uint_as_float(__builtin_amdgcn_readfirstlane(__float_as_uint(DDf)));
  const float Acu = __uint_as_float(__builtin_amdgcn_readfirstlane(__float_as_uint(Acf)));
  const float PAf = DT + 6.f * Acu;
  const float P0f = 15.f * (DT + Acu);
  const float P0u = __uint_as_float(__builtin_amdgcn_readfirstlane(__float_as_uint(P0f)));
  const f32x2 kDD  = {DDu, DDu};
  const f32x2 kP0  = {P0u, P0u};
  const f32x2 k15  = {15.f, 15.f};
  const f32x2 kPAv = {PAf, PAf};
  const f32x2 k6v  = {6.f, 6.f};

  const ushort* p = proj + (size_t)plane * (HW * HW)
                  + (size_t)(w * 16 + ly * 4) * HW + lx * 4;

  f32x2 u[4][2];
#pragma unroll
  for (int r = 0; r < 4; r++) {
    ushort4 v = *(const ushort4*)(p + r * HW);
    u[r][0].x = __uint_as_float((uint32_t)v.x << 16);
    u[r][0].y = __uint_as_float((uint32_t)v.y << 16);
    u[r][1].x = __uint_as_float((uint32_t)v.z << 16);
    u[r][1].y = __uint_as_float((uint32_t)v.w << 16);
  }

  auto pair2 = [&](f32x2 svA, f32x2 svB, f32x2 s4A, f32x2 s4B,
                   f32x2& zA, f32x2& zB) {
    f32x2 yA = pk_mul(svA, svA), yB = pk_mul(svB, svB);
    f32x2 tA = pk_fma_addk(yA, kPAv, kP0);
    f32x2 tB = pk_fma_addk(yB, kPAv, kP0);
    f32x2 nA = pk_mul(svA, tA);
    f32x2 nB = pk_mul(svB, tB);
    f32x2 dA = pk_fma_addk(yA, k6v, k15);
    f32x2 dB = pk_fma_addk(yB, k6v, k15);
    float pA = dA.x * dA.y, qB = dB.x * dB.y;
    float rr = __builtin_amdgcn_rcpf(pA * qB);
    float qr = qB * rr, pr = pA * rr;
    f32x2 iA; iA.x = dA.y * qr; iA.y = dA.x * qr;
    f32x2 iB; iB.x = dB.y * pr; iB.y = dB.x * pr;
    zA = pk_fma_s1(s4A, kDD, pk_mul(nA, iA));
    zB = pk_fma_s1(s4B, kDD, pk_mul(nB, iB));
  };

  const int base = w * 8 + ly * 2;

  // prologue: zero sentinels (slots 0 & 33, both buffers) + publish OLD rows
  {
    int bsel = tid >> 7;
    int ssel = (tid >> 6) & 1;
    bnd[bsel][ssel * 33][lane] = 0.f;
  }
  {
    float4 pub0; pub0.x = u[0][0].x; pub0.y = u[0][0].y;
    pub0.z = u[0][1].x; pub0.w = u[0][1].y;
    *(float4*)&bnd[0][base + 1][lx * 4] = pub0;
    float4 pub3; pub3.x = u[3][0].x; pub3.y = u[3][0].y;
    pub3.z = u[3][1].x; pub3.w = u[3][1].y;
    *(float4*)&bnd[0][base + 2][lx * 4] = pub3;
  }
  __syncthreads();

#pragma unroll 1
  for (int step = 0; step < NSTEP; step++) {
    const int rb = step & 1, wb = rb ^ 1;
    float4 thv = *(const float4*)&bnd[rb][base][lx * 4];
    float4 bhv = *(const float4*)&bnd[rb][base + 3][lx * 4];
    f32x2 th0 = {thv.x, thv.y}, th1 = {thv.z, thv.w};
    f32x2 bh0 = {bhv.x, bhv.y}, bh1 = {bhv.z, bhv.w};

    f32x2 prev0 = th0, prev1 = th1;
#pragma unroll
    for (int r = 0; r < 4; r++) {
      f32x2 sv0 = u[r][0], sv1 = u[r][1];
      float lfv = dpp_from_left(sv1.y);
      float rtv = dpp_from_right(sv0.x);
      f32x2 dn0 = (r < 3) ? u[r + 1][0] : bh0;
      f32x2 dn1 = (r < 3) ? u[r + 1][1] : bh1;
      f32x2 hs0, hs1;
      hs0.x = lfv + sv0.y;   hs0.y = sv0.x + sv1.x;
      hs1.x = sv0.y + sv1.y; hs1.y = sv1.x + rtv;
      f32x2 s40 = pk_add(pk_add(prev0, dn0), hs0);
      f32x2 s41 = pk_add(pk_add(prev1, dn1), hs1);
      pair2(sv0, sv1, s40, s41, u[r][0], u[r][1]);
      prev0 = sv0; prev1 = sv1;
    }

    float4 pub0; pub0.x = u[0][0].x; pub0.y = u[0][0].y;
    pub0.z = u[0][1].x; pub0.w = u[0][1].y;
    *(float4*)&bnd[wb][base + 1][lx * 4] = pub0;
    float4 pub3; pub3.x = u[3][0].x; pub3.y = u[3][0].y;
    pub3.z = u[3][1].x; pub3.w = u[3][1].y;
    *(float4*)&bnd[wb][base + 2][lx * 4] = pub3;
    __syncthreads();
  }

  float s = 0.f;
#pragma unroll
  for (int r = 0; r < 4; r++)
#pragma unroll
    for (int q = 0; q < 2; q++) s += u[r][q].x + u[r][q].y;
#pragma unroll
  for (int off = 32; off > 0; off >>= 1) s += __shfl_xor(s, off);
  if (lane == 0) psum[w] = s;
  __syncthreads();
  if (w == 0 && lane == 0)
    out[plane] = (psum[0] + psum[1] + psum[2] + psum[3]) * (1.f / (HW * HW));
}

// ---------------------------------------------------------------------------
extern "C" void kernel_launch(void* const* d_in, const int* in_sizes, int n_in,
                              void* d_out, int out_size, void* d_ws, size_t ws_size,
                              hipStream_t stream) {
  const float* x    = (const float*)d_in[0];
  const float* W    = (const float*)d_in[1];
  const float* bias = (const float*)d_in[2];
  const float* dc   = (const float*)d_in[3];
  float* out   = (float*)d_out;
  ushort* proj = (ushort*)d_ws;   // BATCH*DIM*SEQ*2 = 32 MB (bf16)

  dim3 g1(DIM / 128, SEQ / 128, BATCH);
  gemm_proj_mfma<<<g1, 256, 0, stream>>>(x, W, bias, proj);

  evolve_kernel<<<BATCH * DIM, 256, 0, stream>>>(proj, dc, out);
}